// Round 6
// baseline (245.867 us; speedup 1.0000x reference)
//
#include <hip/hip_runtime.h>
#include <stdint.h>

// ---------------------------------------------------------------------------
// GPT2 attention forward, fp32 in/out, bf16 MFMA internally.
// Round 19: attn occupancy 2 -> 4 waves/SIMD via LDS halving. r18 (65us)
// left ~50% stall at 2 waves/SIMD; VGPR (128) permits 16 waves/CU but LDS
// (16KB/wave) capped 8. r19: single 8KB buffer/wave (K->P union, next STAGE
// issued mid-PV after pb regs are read, lgkm-fenced: keeps ~600cy overlap).
// 512 uniform blocks x 8 waves: block = (head, strip-pair (63-p, p)), two
// phases, 8-way split-K at 64-key halves (residue v / 7-v complementary) ->
// perfect balance with NO dispatch-map assumptions (2 identical blocks/CU).
// Merge: r15's proven 3-round LDS tree. LDS 67584B -> 2 blocks/CU = 16
// waves/CU. launch_bounds(512,2): empirically (r15) caps VGPR at 128.
// Spill sentinel: FETCH must stay ~12.5MB.
// ---------------------------------------------------------------------------

typedef __bf16 bf16x8 __attribute__((ext_vector_type(8)));
typedef float f32x4 __attribute__((ext_vector_type(4)));

#define QSCALE 0.18033688011112042f  // 0.125 * log2(e): softmax in exp2 domain

__device__ __forceinline__ f32x4 mfma16(bf16x8 a, bf16x8 b, f32x4 c) {
  return __builtin_amdgcn_mfma_f32_16x16x32_bf16(a, b, c, 0, 0, 0);
}

// async global->LDS, 16B/lane: lane i's 16B -> ldsbase + i*16 (wave-uniform base)
__device__ __forceinline__ void g2l16(const void* g, void* l) {
  __builtin_amdgcn_global_load_lds(
      (const __attribute__((address_space(1))) unsigned int*)g,
      (__attribute__((address_space(3))) unsigned int*)l,
      16, 0, 0);
}

__device__ __forceinline__ uint16_t f2bf(float f) {
  unsigned int u = __builtin_bit_cast(unsigned int, f);
  u += 0x7fffu + ((u >> 16) & 1u);
  return (uint16_t)(u >> 16);
}

// pack high halves of two fp32 (truncate-to-bf16) into one dword: 1 VALU op.
__device__ __forceinline__ unsigned int pack_hi(float lo, float hi) {
  return __builtin_amdgcn_perm(__builtin_bit_cast(unsigned int, hi),
                               __builtin_bit_cast(unsigned int, lo), 0x07060302u);
}

// ---------------------------------------------------------------------------
// fp32 -> bf16 elementwise, 8 elements/thread.
// ---------------------------------------------------------------------------
__global__ __launch_bounds__(256) void f2b_k(const float* __restrict__ in,
                                             uint16_t* __restrict__ out, int n) {
  const int base = (blockIdx.x * 256 + threadIdx.x) * 8;
  if (base >= n) return;
  float4 a = *(const float4*)(in + base);
  float4 b = *(const float4*)(in + base + 4);
  uint16_t t[8];
  t[0] = f2bf(a.x); t[1] = f2bf(a.y); t[2] = f2bf(a.z); t[3] = f2bf(a.w);
  t[4] = f2bf(b.x); t[5] = f2bf(b.y); t[6] = f2bf(b.z); t[7] = f2bf(b.w);
  *(int4*)(out + base) = *(const int4*)t;
}

// ---------------------------------------------------------------------------
// merged convert+transpose for both weights: bx<48 -> W_attn (C=3072),
// else W_proj (C=1024). out[c][r] = in[r][c], R=1024. grid (64,16).
// ---------------------------------------------------------------------------
__global__ __launch_bounds__(256) void transpose2_f2b(const float* __restrict__ inA,
                                                      uint16_t* __restrict__ outA,
                                                      const float* __restrict__ inB,
                                                      uint16_t* __restrict__ outB) {
  __shared__ float t[64][65];
  const int tx = threadIdx.x & 15;
  const int ty = threadIdx.x >> 4;
  const bool isA = blockIdx.x < 48;
  const float* in = isA ? inA : inB;
  uint16_t* out = isA ? outA : outB;
  const int C = isA ? 3072 : 1024;
  const int bx = isA ? blockIdx.x : (blockIdx.x - 48);
  const int r0 = blockIdx.y * 64, c0 = bx * 64;
#pragma unroll
  for (int rr = ty; rr < 64; rr += 16) {
    float4 v = *(const float4*)(in + (size_t)(r0 + rr) * C + c0 + tx * 4);
    t[rr][tx * 4 + 0] = v.x; t[rr][tx * 4 + 1] = v.y;
    t[rr][tx * 4 + 2] = v.z; t[rr][tx * 4 + 3] = v.w;
  }
  __syncthreads();
#pragma unroll
  for (int cc = ty; cc < 64; cc += 16) {
    uint16_t tmp[4];
#pragma unroll
    for (int j = 0; j < 4; j++) tmp[j] = f2bf(t[tx * 4 + j][cc]);
    *(uint2*)(out + (size_t)(c0 + cc) * 1024 + r0 + tx * 4) = *(const uint2*)tmp;
  }
}

// ---------------------------------------------------------------------------
// bt-form GEMM: C[m][n] = A[m][:].Bt[n][:] + bias[n]. A,Bt bf16; bias fp32.
// K=1024, tile 128x128, async global_load_lds staging (width 16).
// EPI==0: QKV scatter (Q prescaled by QSCALE; outV = V^T tile-blocked
//         [h][jt][d][128]) -> bf16
// EPI==1: plain fp32 epilogue (outF[m*1024+n])
// ---------------------------------------------------------------------------
template <int EPI>
__global__ __launch_bounds__(256) void gemm_bt(const uint16_t* __restrict__ A,
                                               const uint16_t* __restrict__ Bt,
                                               const float* __restrict__ bias,
                                               uint16_t* __restrict__ outQ,
                                               uint16_t* __restrict__ outK,
                                               uint16_t* __restrict__ outV,
                                               float* __restrict__ outF) {
  __shared__ __align__(16) uint16_t lA[128 * 32];
  __shared__ __align__(16) uint16_t lB[128 * 32];
  const int tid = threadIdx.x;
  const int w = tid >> 6, lane = tid & 63;
  const int quad = lane >> 4, c16 = lane & 15;
  const int m0 = blockIdx.y * 128, n0 = blockIdx.x * 128;

  f32x4 acc[4][4];
#pragma unroll
  for (int i = 0; i < 4; i++)
#pragma unroll
    for (int j = 0; j < 4; j++) acc[i][j] = f32x4{0.f, 0.f, 0.f, 0.f};

  // LDS row = 64B = 4 chunks of 16B; chunk swizzle c' = c ^ ((row>>1)&3).
  for (int k0 = 0; k0 < 1024; k0 += 32) {
    __syncthreads();
#pragma unroll
    for (int ii = 0; ii < 2; ii++) {
      const int instr = w * 2 + ii;
      const int p16 = instr * 64 + lane;  // 0..511
      const int row = p16 >> 2, cp = p16 & 3;
      const int c = cp ^ ((row >> 1) & 3);
      g2l16(A + (size_t)(m0 + row) * 1024 + k0 + c * 8, (char*)lA + (size_t)instr * 1024);
      g2l16(Bt + (size_t)(n0 + row) * 1024 + k0 + c * 8, (char*)lB + (size_t)instr * 1024);
    }
    __syncthreads();
    bf16x8 af[4], bfr[4];
#pragma unroll
    for (int t = 0; t < 4; t++) {
      const int mr = (w >> 1) * 64 + t * 16 + c16;
      af[t] = *(const bf16x8*)((const char*)lA + mr * 64 + ((quad ^ ((mr >> 1) & 3)) * 16));
      const int nr = (w & 1) * 64 + t * 16 + c16;
      bfr[t] = *(const bf16x8*)((const char*)lB + nr * 64 + ((quad ^ ((nr >> 1) & 3)) * 16));
    }
#pragma unroll
    for (int i = 0; i < 4; i++)
#pragma unroll
      for (int j = 0; j < 4; j++) acc[i][j] = mfma16(af[i], bfr[j], acc[i][j]);
  }

  // epilogue. C/D layout per 16x16 tile: col = lane&15, row = quad*4+r.
  const int mbase = m0 + (w >> 1) * 64;
  const int nbase = n0 + (w & 1) * 64;
  float bv[4];
#pragma unroll
  for (int j = 0; j < 4; j++) bv[j] = bias[nbase + j * 16 + c16];
#pragma unroll
  for (int i = 0; i < 4; i++) {
#pragma unroll
    for (int j = 0; j < 4; j++) {
      const int n = nbase + j * 16 + c16;
#pragma unroll
      for (int r = 0; r < 4; r++) {
        const int m = mbase + i * 16 + quad * 4 + r;
        float fv = acc[i][j][r] + bv[j];
        if (EPI == 0) {
          const int region = n >> 10;  // 0=Q 1=K 2=V (uniform per block)
          const int cr = n & 1023;
          const int h = cr >> 6, d = cr & 63;
          if (region == 0)      outQ[((size_t)(h << 12) + m) * 64 + d] = f2bf(fv * QSCALE);
          else if (region == 1) outK[((size_t)(h << 12) + m) * 64 + d] = f2bf(fv);
          else                  outV[(((size_t)(h * 32 + (m >> 7)) * 64 + d) << 7) + (m & 127)] = f2bf(fv);
        } else {
          outF[(size_t)m * 1024 + n] = fv;
        }
      }
    }
  }
}

// ---------------------------------------------------------------------------
// Flash attention. 512 UNIFORM blocks (one per (head, strip-pair)), 8 waves.
// Phase 0: strip 63-p; phase 1: strip p. 8-way split-K at 64-key halves:
// wave v takes hh ≡ v (mod 8) in phase 0, ≡ 7-v in phase 1 (complementary ->
// ~9 halves/wave uniform). Per wave ONE 8KB LDS buffer: K(hh) staged by
// global_load_lds (source-swizzled) -> kfr regs -> P(hh) overwrites -> pb2
// regs -> [lgkm0] STAGE K(hh+8) lands over it during PV MFMAs. vmcnt(0) at
// half top. Merge: 3-round pairwise LDS tree (r15's proven pattern) in the
// 64KB lX area, then all 512 threads write bf16 Ob. 2 blocks/CU = 16
// waves/CU = 4 waves/SIMD.
// ---------------------------------------------------------------------------
__global__ __launch_bounds__(512, 2) void attn_kernel(const uint16_t* __restrict__ Qb,
                                                      const uint16_t* __restrict__ Kb,
                                                      const uint16_t* __restrict__ Vtb,
                                                      uint16_t* __restrict__ Ob) {
  __shared__ __align__(16) uint16_t lX[8][64 * 64];  // 8KB/wave K->P; union: fp32 merge regions
  __shared__ float lL[8][64];                        // per-wave l partials
  const int tid = threadIdx.x;
  const int v = tid >> 6;            // wave 0..7
  const int lane = tid & 63;
  const int quad = lane >> 4, c16 = lane & 15;
  const int c7 = c16 & 7;
  const int bid = blockIdx.x;
  const int h = bid & 15;            // head pinned to XCD
  const int p = bid >> 4;            // strip pair 0..31: strips (63-p, p)

  // staging source offset (elements): lane i covers key_local=i>>3, 16B
  // chunk (i&7)^(i>>3) (pre-swizzle so LDS[key][c] holds K[key][c^(key&7)]).
  const int stage_off = (lane >> 3) * 64 + (((lane & 7) ^ (lane >> 3)) << 3);

#define STAGE_K(HH)                                                             \
  {                                                                             \
    const uint16_t* kbh_ = Kb + ((size_t)(h << 12) + (HH) * 64) * 64;           \
    _Pragma("unroll") for (int s = 0; s < 8; s++)                               \
        g2l16(kbh_ + s * 512 + stage_off, (char*)lX[v] + s * 1024);             \
  }
#define SPILL_O(region)                                                         \
  {                                                                             \
    float* oL = (float*)((char*)lX + (region) * 16384);                         \
    _Pragma("unroll") for (int mt = 0; mt < 4; mt++)                            \
        _Pragma("unroll") for (int ntq = 0; ntq < 4; ntq++) {                   \
      const int q = ntq * 16 + c16;                                             \
      const int db = mt * 16 + quad * 4;                                        \
      *(f32x4*)(oL + q * 64 + (db ^ ((q & 7) << 3))) = o[mt][ntq];              \
    }                                                                           \
  }
#define ADD_O(region)                                                           \
  {                                                                             \
    const float* oL = (const float*)((char*)lX + (region) * 16384);             \
    _Pragma("unroll") for (int mt = 0; mt < 4; mt++)                            \
        _Pragma("unroll") for (int ntq = 0; ntq < 4; ntq++) {                   \
      const int q = ntq * 16 + c16;                                             \
      const int db = mt * 16 + quad * 4;                                        \
      o[mt][ntq] += *(const f32x4*)(oL + q * 64 + (db ^ ((q & 7) << 3)));       \
    }                                                                           \
  }

  for (int phase = 0; phase < 2; ++phase) {
    const int sw = phase ? p : (63 - p);     // this phase's 64-q strip
    const int rv = phase ? (7 - v) : v;      // this wave's key-half residue
    const int q0w = sw * 64;

    // Q fragments (B-operand), 4 q-subtiles: lane q(n)=c16, k(d)=kc*32+quad*8+j
    bf16x8 qf[4][2];
#pragma unroll
    for (int ntq = 0; ntq < 4; ntq++)
#pragma unroll
      for (int kc = 0; kc < 2; kc++) {
        int4 vv = *(const int4*)(Qb + ((size_t)(h << 12) + q0w + ntq * 16 + c16) * 64 + kc * 32 + quad * 8);
        qf[ntq][kc] = __builtin_bit_cast(bf16x8, vv);
      }

    float ls[4] = {0.f, 0.f, 0.f, 0.f};
    f32x4 o[4][4];
#pragma unroll
    for (int i = 0; i < 4; i++)
#pragma unroll
      for (int nq = 0; nq < 4; nq++) o[i][nq] = f32x4{0.f, 0.f, 0.f, 0.f};

    if (rv <= sw) STAGE_K(rv);  // prologue stage (fully exposed once/phase)

    for (int hh = rv; hh <= sw; hh += 8) {
      asm volatile("s_waitcnt vmcnt(0)" ::: "memory");  // K(hh) staged

      // ---- K fragments from LDS (swizzled): 8 x ds_read_b128
      bf16x8 kfr[2][4];
      const char* kx = (const char*)lX[v] + c16 * 128;
#pragma unroll
      for (int kc = 0; kc < 2; kc++)
#pragma unroll
        for (int mt = 0; mt < 4; mt++)
          kfr[kc][mt] = *(const bf16x8*)(kx + mt * 2048 + (((kc * 4 + quad) ^ c7) << 4));

      // ---- QK^T + fixed-M softmax; P overwrites lX[v] (K already in kfr)
#pragma unroll
      for (int qp = 0; qp < 2; qp++) {
        f32x4 st[4][2];
#pragma unroll
        for (int mt = 0; mt < 4; mt++) {
          st[mt][0] = f32x4{0.f, 0.f, 0.f, 0.f};
          st[mt][1] = f32x4{0.f, 0.f, 0.f, 0.f};
        }
        __builtin_amdgcn_s_setprio(1);
#pragma unroll
        for (int kc = 0; kc < 2; kc++)
#pragma unroll
          for (int mt = 0; mt < 4; mt++) {
            st[mt][0] = mfma16(kfr[kc][mt], qf[qp * 2 + 0][kc], st[mt][0]);
            st[mt][1] = mfma16(kfr[kc][mt], qf[qp * 2 + 1][kc], st[mt][1]);
          }
        __builtin_amdgcn_s_setprio(0);

        // causal mask on the diagonal half (wave-uniform branch); both key
        // and q are offsets from 64*sw here.
        if (hh == sw) {
#pragma unroll
          for (int nt = 0; nt < 2; nt++) {
            const int ql = qp * 32 + nt * 16 + c16;
#pragma unroll
            for (int mt = 0; mt < 4; mt++)
#pragma unroll
              for (int rr = 0; rr < 4; rr++) {
                const int key = mt * 16 + quad * 4 + rr;
                if (key > ql) st[mt][nt][rr] = -1.0e9f;
              }
          }
        }

        // P = exp2(s); l += sum(P); pack P -> lX[v] rows [q][64 keys].
#pragma unroll
        for (int nt = 0; nt < 2; nt++) {
          float sum0 = 0.f, sum1 = 0.f;
          const int prow = qp * 32 + nt * 16 + c16;
          const size_t pbase = (size_t)prow * 128;
#pragma unroll
          for (int mt = 0; mt < 4; mt++) {
            float p0 = __builtin_amdgcn_exp2f(st[mt][nt][0]);
            float p1 = __builtin_amdgcn_exp2f(st[mt][nt][1]);
            float p2 = __builtin_amdgcn_exp2f(st[mt][nt][2]);
            float p3 = __builtin_amdgcn_exp2f(st[mt][nt][3]);
            sum0 += p0 + p1;
            sum1 += p2 + p3;
            const unsigned int lo = pack_hi(p0, p1);
            const unsigned int hi = pack_hi(p2, p3);
            const int chunk = mt * 2 + (quad >> 1);  // 8 x 16B chunks per row
            uint2* dst = (uint2*)((char*)lX[v] + pbase +
                                  ((chunk ^ (prow & 7)) << 4) + (quad & 1) * 8);
            *dst = make_uint2(lo, hi);
          }
          float sum = sum0 + sum1;
          sum += __shfl_xor(sum, 16);
          sum += __shfl_xor(sum, 32);
          ls[qp * 2 + nt] += sum;
        }
      }
      // lX[v] now holds P; same-wave write->read (in order): no barrier.

      // ---- read ALL P fragments into regs, then free the buffer for the
      //      next K stage (overlaps the PV MFMA block below).
      bf16x8 pb2[2][4];
#pragma unroll
      for (int kc2 = 0; kc2 < 2; kc2++)
#pragma unroll
        for (int ntq = 0; ntq < 4; ntq++) {
          const int prow = ntq * 16 + c16;
          pb2[kc2][ntq] = *(const bf16x8*)((const char*)lX[v] + (size_t)prow * 128 +
                                           (((kc2 * 4 + quad) ^ (prow & 7)) << 4));
        }
      asm volatile("s_waitcnt lgkmcnt(0)" ::: "memory");  // pb2 + P writes done
      if (hh + 8 <= sw) STAGE_K(hh + 8);                  // lands over buffer

      // ---- O^T += Vt(hh) . P^T : vf transient (16 regs)
      const int jt = hh >> 1;
      const uint16_t* vbase = Vtb + (((size_t)(h * 32 + jt) * 64) << 7);
#pragma unroll
      for (int kc2 = 0; kc2 < 2; kc2++) {
        int4 vf[4];
#pragma unroll
        for (int mt = 0; mt < 4; mt++)
          vf[mt] = *(const int4*)(vbase + ((mt * 16 + c16) << 7) +
                                  ((hh & 1) * 8 + kc2 * 4 + quad) * 8);
        __builtin_amdgcn_s_setprio(1);
#pragma unroll
        for (int mt = 0; mt < 4; mt++) {
          bf16x8 a = __builtin_bit_cast(bf16x8, vf[mt]);
#pragma unroll
          for (int ntq = 0; ntq < 4; ntq++)
            o[mt][ntq] = mfma16(a, pb2[kc2][ntq], o[mt][ntq]);
        }
        __builtin_amdgcn_s_setprio(0);
      }
    }

    asm volatile("s_waitcnt vmcnt(0)" ::: "memory");  // drain before lX reuse

    // ---- per-wave l partials
    if (quad == 0) {
#pragma unroll
      for (int ntq = 0; ntq < 4; ntq++) lL[v][ntq * 16 + c16] = ls[ntq];
    }

    // ---- split-K merge: 3-round pairwise tree in the lX area (4 x 16KB
    // fp32 regions), r15's proven pattern.
    __syncthreads();                 // all waves done with their buffers
    if (v >= 4) SPILL_O(v - 4);      // waves 4-7 -> regions 0-3
    __syncthreads();
    if (v < 4) ADD_O(v);             // waves 0-3 absorb
    __syncthreads();
    if (v == 2 || v == 3) SPILL_O(v - 2);
    __syncthreads();
    if (v < 2) ADD_O(v);
    __syncthreads();
    if (v < 2) SPILL_O(v);           // region0 = even sum, region1 = odd sum
    __syncthreads();

    // ---- final: all 512 threads. q = tid&63, 8 d's each; divide by l, write.
    {
      const int q = tid & 63, dg = tid >> 6;  // dg 0..7
      float lsum = 0.f;
#pragma unroll
      for (int i = 0; i < 8; i++) lsum += lL[i][q];
      const float inv = 1.f / lsum;
      const float* r0 = (const float*)lX;
      const float* r1 = (const float*)((char*)lX + 16384);
      const int off = q * 64 + ((dg ^ (q & 7)) << 3);  // 8 consecutive floats
      f32x4 a0 = *(const f32x4*)(r0 + off);
      f32x4 a1 = *(const f32x4*)(r0 + off + 4);
      f32x4 b0 = *(const f32x4*)(r1 + off);
      f32x4 b1 = *(const f32x4*)(r1 + off + 4);
      uint16_t t[8] __attribute__((aligned(16)));
#pragma unroll
      for (int i = 0; i < 4; i++) t[i] = f2bf((a0[i] + b0[i]) * inv);
#pragma unroll
      for (int i = 0; i < 4; i++) t[4 + i] = f2bf((a1[i] + b1[i]) * inv);
      *(int4*)(Ob + (size_t)(q0w + q) * 1024 + h * 64 + dg * 8) = *(const int4*)t;
    }
    if (phase == 0) __syncthreads();  // lX/lL reused by phase 1
  }
#undef STAGE_K
#undef SPILL_O
#undef ADD_O
}

// ---------------------------------------------------------------------------
extern "C" void kernel_launch(void* const* d_in, const int* in_sizes, int n_in,
                              void* d_out, int out_size, void* d_ws, size_t ws_size,
                              hipStream_t stream) {
  const float* x      = (const float*)d_in[0];   // fp32 [1][4096][1024]
  // d_in[1] = attention_mask (fp32): analytically causal, never read
  const float* W_attn = (const float*)d_in[2];   // fp32 [1024][3072]
  const float* b_attn = (const float*)d_in[3];   // fp32 [3072]
  const float* W_proj = (const float*)d_in[4];   // fp32 [1024][1024]
  const float* b_proj = (const float*)d_in[5];   // fp32 [1024]
  float* out = (float*)d_out;                    // fp32 [4096][1024]

  // Workspace (48 MB).
  char* ws = (char*)d_ws;
  uint16_t* Ob  = (uint16_t*)(ws);                    // [0,8MB): attn out bf16 [4096][1024]
  uint16_t* wtA = (uint16_t*)(ws + 8388608);          // [8,14MB): W_attn^T bf16
  uint16_t* wtP = (uint16_t*)(ws + 14680064);         // [14,16MB): W_proj^T bf16
  uint16_t* Qb  = (uint16_t*)(ws + 16777216);         // [16,24MB): Q bf16 (prescaled QSCALE)
  uint16_t* Kb  = (uint16_t*)(ws + 25165824);         // [24,32MB): K bf16
  uint16_t* Vtb = (uint16_t*)(ws + 33554432);         // [32,40MB): V^T tile-blocked bf16
  uint16_t* xb  = (uint16_t*)(ws + 41943040);         // [40,48MB): x bf16

  f2b_k<<<2048, 256, 0, stream>>>(x, xb, 4096 * 1024);
  transpose2_f2b<<<dim3(64, 16), 256, 0, stream>>>(W_attn, wtA, W_proj, wtP);
  gemm_bt<0><<<dim3(24, 32), 256, 0, stream>>>(xb, wtA, b_attn, Qb, Kb, Vtb, nullptr);
  attn_kernel<<<dim3(512), 512, 0, stream>>>(Qb, Kb, Vtb, Ob);
  gemm_bt<1><<<dim3(8, 32), 256, 0, stream>>>(Ob, wtP, b_proj, nullptr, nullptr, nullptr, out);
}

// Round 7
// 238.377 us; speedup vs baseline: 1.0314x; 1.0314x over previous
//
#include <hip/hip_runtime.h>
#include <stdint.h>

// ---------------------------------------------------------------------------
// GPT2 attention forward, fp32 in/out, bf16 MFMA internally.
// Round 20: attn reverted to r18 (65.4us proven; r19's single-buffer 8-wave
// variant regressed to 79us - overlap window too short). This round targets
// the OTHER ~174us: the two GEMMs. gemm1 runs at 1 block/CU (grid 256) with
// zero inter-block overlap; both gemms expose stage latency (stage;
// drain-barrier; compute). gemm_bt rewritten as 2-phase double-buffered
// staging (issue next tile's global_load_lds BEFORE computing current, one
// vmcnt(0)+barrier per K-step) + XCD-aware block swizzle (grids 768/256 are
// 8-divisible -> bijective). LDS 32KB -> >=4 blocks/CU capacity unchanged.
// ---------------------------------------------------------------------------

typedef __bf16 bf16x8 __attribute__((ext_vector_type(8)));
typedef float f32x4 __attribute__((ext_vector_type(4)));

#define QSCALE 0.18033688011112042f  // 0.125 * log2(e): softmax in exp2 domain

__device__ __forceinline__ f32x4 mfma16(bf16x8 a, bf16x8 b, f32x4 c) {
  return __builtin_amdgcn_mfma_f32_16x16x32_bf16(a, b, c, 0, 0, 0);
}

// async global->LDS, 16B/lane: lane i's 16B -> ldsbase + i*16 (wave-uniform base)
__device__ __forceinline__ void g2l16(const void* g, void* l) {
  __builtin_amdgcn_global_load_lds(
      (const __attribute__((address_space(1))) unsigned int*)g,
      (__attribute__((address_space(3))) unsigned int*)l,
      16, 0, 0);
}

__device__ __forceinline__ uint16_t f2bf(float f) {
  unsigned int u = __builtin_bit_cast(unsigned int, f);
  u += 0x7fffu + ((u >> 16) & 1u);
  return (uint16_t)(u >> 16);
}

// pack high halves of two fp32 (truncate-to-bf16) into one dword: 1 VALU op.
__device__ __forceinline__ unsigned int pack_hi(float lo, float hi) {
  return __builtin_amdgcn_perm(__builtin_bit_cast(unsigned int, hi),
                               __builtin_bit_cast(unsigned int, lo), 0x07060302u);
}

// ---------------------------------------------------------------------------
// fp32 -> bf16 elementwise, 8 elements/thread.
// ---------------------------------------------------------------------------
__global__ __launch_bounds__(256) void f2b_k(const float* __restrict__ in,
                                             uint16_t* __restrict__ out, int n) {
  const int base = (blockIdx.x * 256 + threadIdx.x) * 8;
  if (base >= n) return;
  float4 a = *(const float4*)(in + base);
  float4 b = *(const float4*)(in + base + 4);
  uint16_t t[8];
  t[0] = f2bf(a.x); t[1] = f2bf(a.y); t[2] = f2bf(a.z); t[3] = f2bf(a.w);
  t[4] = f2bf(b.x); t[5] = f2bf(b.y); t[6] = f2bf(b.z); t[7] = f2bf(b.w);
  *(int4*)(out + base) = *(const int4*)t;
}

// ---------------------------------------------------------------------------
// merged convert+transpose for both weights: bx<48 -> W_attn (C=3072),
// else W_proj (C=1024). out[c][r] = in[r][c], R=1024. grid (64,16).
// ---------------------------------------------------------------------------
__global__ __launch_bounds__(256) void transpose2_f2b(const float* __restrict__ inA,
                                                      uint16_t* __restrict__ outA,
                                                      const float* __restrict__ inB,
                                                      uint16_t* __restrict__ outB) {
  __shared__ float t[64][65];
  const int tx = threadIdx.x & 15;
  const int ty = threadIdx.x >> 4;
  const bool isA = blockIdx.x < 48;
  const float* in = isA ? inA : inB;
  uint16_t* out = isA ? outA : outB;
  const int C = isA ? 3072 : 1024;
  const int bx = isA ? blockIdx.x : (blockIdx.x - 48);
  const int r0 = blockIdx.y * 64, c0 = bx * 64;
#pragma unroll
  for (int rr = ty; rr < 64; rr += 16) {
    float4 v = *(const float4*)(in + (size_t)(r0 + rr) * C + c0 + tx * 4);
    t[rr][tx * 4 + 0] = v.x; t[rr][tx * 4 + 1] = v.y;
    t[rr][tx * 4 + 2] = v.z; t[rr][tx * 4 + 3] = v.w;
  }
  __syncthreads();
#pragma unroll
  for (int cc = ty; cc < 64; cc += 16) {
    uint16_t tmp[4];
#pragma unroll
    for (int j = 0; j < 4; j++) tmp[j] = f2bf(t[tx * 4 + j][cc]);
    *(uint2*)(out + (size_t)(c0 + cc) * 1024 + r0 + tx * 4) = *(const uint2*)tmp;
  }
}

// ---------------------------------------------------------------------------
// bt-form GEMM: C[m][n] = A[m][:].Bt[n][:] + bias[n]. A,Bt bf16; bias fp32.
// K=1024, tile 128x128. r20: 2-phase double-buffered global_load_lds staging
// (issue next K-step's loads BEFORE computing current; single vmcnt(0)+
// barrier per step) + XCD-aware block swizzle (nwg % 8 == 0 for both grids).
// EPI==0: QKV scatter (Q prescaled by QSCALE; outV = V^T tile-blocked
//         [h][jt][d][128]) -> bf16
// EPI==1: plain fp32 epilogue (outF[m*1024+n])
// ---------------------------------------------------------------------------
template <int EPI>
__global__ __launch_bounds__(256) void gemm_bt(const uint16_t* __restrict__ A,
                                               const uint16_t* __restrict__ Bt,
                                               const float* __restrict__ bias,
                                               uint16_t* __restrict__ outQ,
                                               uint16_t* __restrict__ outK,
                                               uint16_t* __restrict__ outV,
                                               float* __restrict__ outF) {
  __shared__ __align__(16) uint16_t lA[2][128 * 32];
  __shared__ __align__(16) uint16_t lB[2][128 * 32];
  const int tid = threadIdx.x;
  const int w = tid >> 6, lane = tid & 63;
  const int quad = lane >> 4, c16 = lane & 15;

  // XCD-aware swizzle: hw block L (XCD ~ L%8) takes work item
  // (L%8)*(nwg/8) + L/8 -> each XCD gets a contiguous chunk of m-rows.
  const int nwg = gridDim.x * gridDim.y;
  const int lin = blockIdx.y * gridDim.x + blockIdx.x;
  const int swz = (lin & 7) * (nwg >> 3) + (lin >> 3);
  const int m0 = (swz / gridDim.x) * 128, n0 = (swz % gridDim.x) * 128;

  f32x4 acc[4][4];
#pragma unroll
  for (int i = 0; i < 4; i++)
#pragma unroll
    for (int j = 0; j < 4; j++) acc[i][j] = f32x4{0.f, 0.f, 0.f, 0.f};

  // staging geometry: LDS row = 64B = 4 chunks of 16B; chunk swizzle
  // c' = c ^ ((row>>1)&3). Per wave: 2 instrs each for A and B.
  const int instr = w * 2;  // this wave's first 1KB chunk index (0,2,4,6)
#define STAGE(BUF, K0)                                                          \
  _Pragma("unroll") for (int ii = 0; ii < 2; ii++) {                            \
    const int p16 = (instr + ii) * 64 + lane;                                   \
    const int row = p16 >> 2, cp = p16 & 3;                                     \
    const int c = cp ^ ((row >> 1) & 3);                                        \
    g2l16(A + (size_t)(m0 + row) * 1024 + (K0) + c * 8,                         \
          (char*)lA[BUF] + (size_t)(instr + ii) * 1024);                        \
    g2l16(Bt + (size_t)(n0 + row) * 1024 + (K0) + c * 8,                        \
          (char*)lB[BUF] + (size_t)(instr + ii) * 1024);                        \
  }

  // prologue: stage K-step 0 into buf 0, drain, barrier.
  STAGE(0, 0);
  asm volatile("s_waitcnt vmcnt(0)" ::: "memory");
  __syncthreads();

  int cur = 0;
  for (int k0 = 0; k0 < 1024; k0 += 32) {
    // issue next K-step's stage into the other buffer (overlaps compute)
    if (k0 + 32 < 1024) STAGE(cur ^ 1, k0 + 32);

    bf16x8 af[4], bfr[4];
#pragma unroll
    for (int t = 0; t < 4; t++) {
      const int mr = (w >> 1) * 64 + t * 16 + c16;
      af[t] = *(const bf16x8*)((const char*)lA[cur] + mr * 64 + ((quad ^ ((mr >> 1) & 3)) * 16));
      const int nr = (w & 1) * 64 + t * 16 + c16;
      bfr[t] = *(const bf16x8*)((const char*)lB[cur] + nr * 64 + ((quad ^ ((nr >> 1) & 3)) * 16));
    }
#pragma unroll
    for (int i = 0; i < 4; i++)
#pragma unroll
      for (int j = 0; j < 4; j++) acc[i][j] = mfma16(af[i], bfr[j], acc[i][j]);

    // next stage complete + all waves done reading buf[cur] -> safe to swap.
    __syncthreads();
    cur ^= 1;
  }

  // epilogue. C/D layout per 16x16 tile: col = lane&15, row = quad*4+r.
  const int mbase = m0 + (w >> 1) * 64;
  const int nbase = n0 + (w & 1) * 64;
  float bv[4];
#pragma unroll
  for (int j = 0; j < 4; j++) bv[j] = bias[nbase + j * 16 + c16];
#pragma unroll
  for (int i = 0; i < 4; i++) {
#pragma unroll
    for (int j = 0; j < 4; j++) {
      const int n = nbase + j * 16 + c16;
#pragma unroll
      for (int r = 0; r < 4; r++) {
        const int m = mbase + i * 16 + quad * 4 + r;
        float fv = acc[i][j][r] + bv[j];
        if (EPI == 0) {
          const int region = n >> 10;  // 0=Q 1=K 2=V (uniform per block)
          const int cr = n & 1023;
          const int h = cr >> 6, d = cr & 63;
          if (region == 0)      outQ[((size_t)(h << 12) + m) * 64 + d] = f2bf(fv * QSCALE);
          else if (region == 1) outK[((size_t)(h << 12) + m) * 64 + d] = f2bf(fv);
          else                  outV[(((size_t)(h * 32 + (m >> 7)) * 64 + d) << 7) + (m & 127)] = f2bf(fv);
        } else {
          outF[(size_t)m * 1024 + n] = fv;
        }
      }
    }
  }
#undef STAGE
}

// ---------------------------------------------------------------------------
// Flash attention (r18, proven 65.4us). ONE BLOCK (4 waves, 256 thr) per
// (head, strip). Each wave owns 64 q rows and key tiles j ≡ waveid (mod 4).
// 1024 blocks backfill onto 512 block-slots heavy-first (2 blocks/CU).
// Fixed-M softmax (exp2 domain). K staged one 64-key half AHEAD via
// global_load_lds into per-wave LDS X[2][8KB] (zero VGPR cost), source-side
// XOR swizzle, counted vmcnt(8). K(half) consumed into regs before P(half)
// overwrites the same 8KB. PV reads P from LDS; vf global loads transient.
// Epilogue: X reused as fp32 O^T merge region after vmcnt(0) drain.
// ---------------------------------------------------------------------------
__global__ __launch_bounds__(256, 2) void attn_kernel(const uint16_t* __restrict__ Qb,
                                                      const uint16_t* __restrict__ Kb,
                                                      const uint16_t* __restrict__ Vtb,
                                                      uint16_t* __restrict__ Ob) {
  // per-wave X[2][8KB]: staged K half (swizzled) -> overwritten by P(half);
  // union: epilogue fp32 O^T spill region (16KB/wave).
  __shared__ __align__(16) uint16_t lX[4][2][64 * 64];
  __shared__ float lL[4][64];                         // per-wave l partials
  const int tid = threadIdx.x;
  const int w = tid >> 6;            // split-K residue 0..3 (= wave id)
  const int lane = tid & 63;
  const int quad = lane >> 4, c16 = lane & 15;
  const int c7 = c16 & 7;
  const int bid = blockIdx.x;
  const int h = bid & 15;            // head pinned to XCD
  const int sw = 63 - (bid >> 4);    // 64-q strip, heavy first
  const int q0w = sw * 64;
  const int jmax = sw >> 1;          // last key tile (causal)

  // staging source offset (elements): lane i covers key_local=i>>3 of an
  // 8-key group, 16B chunk (i&7)^(i>>3) (pre-swizzled so LDS[key][c] holds
  // K[key][c ^ (key&7)]; g2l16 dest is linear base + lane*16).
  const int stage_off = (lane >> 3) * 64 + (((lane & 7) ^ (lane >> 3)) << 3);

// stage one 64-key half (8KB = 8 x 1KB instrs) into lX[w][BUF]
#define STAGE_K(BUF, KBH)                                                       \
  _Pragma("unroll") for (int s = 0; s < 8; s++)                                 \
      g2l16((KBH) + s * 512 + stage_off, (char*)lX[w][BUF] + s * 1024);

  // Q fragments (B-operand), 4 q-subtiles: lane q(n)=c16, k(d)=kc*32+quad*8+j
  bf16x8 qf[4][2];
#pragma unroll
  for (int ntq = 0; ntq < 4; ntq++)
#pragma unroll
    for (int kc = 0; kc < 2; kc++) {
      int4 v = *(const int4*)(Qb + ((size_t)(h << 12) + q0w + ntq * 16 + c16) * 64 + kc * 32 + quad * 8);
      qf[ntq][kc] = __builtin_bit_cast(bf16x8, v);
    }

  float ls[4] = {0.f, 0.f, 0.f, 0.f};
  f32x4 o[4][4];
#pragma unroll
  for (int i = 0; i < 4; i++)
#pragma unroll
    for (int nq = 0; nq < 4; nq++) o[i][nq] = f32x4{0.f, 0.f, 0.f, 0.f};

  // prologue: stage half0 of this wave's first tile (dead-but-safe if idle)
  {
    const uint16_t* kb0 = Kb + ((size_t)(h << 12) + w * 128) * 64;
    STAGE_K(0, kb0);
  }

  for (int j = w; j <= jmax; j += 4) {
    const uint16_t* kbase = Kb + ((size_t)(h << 12) + j * 128) * 64;
    const uint16_t* vbase = Vtb + (((size_t)(h * 32 + j) * 64) << 7);

#pragma unroll
    for (int half = 0; half < 2; half++) {
      // issue next-half stage, then wait for CURRENT half's stage:
      // vmcnt(8) = "all but the 8 just-issued are done". Tail: vmcnt(0).
      if (half == 0) {
        STAGE_K(1, kbase + 4096);
        asm volatile("s_waitcnt vmcnt(8)" ::: "memory");
      } else if (j + 4 <= jmax) {
        const uint16_t* kbn = Kb + ((size_t)(h << 12) + (j + 4) * 128) * 64;
        STAGE_K(0, kbn);
        asm volatile("s_waitcnt vmcnt(8)" ::: "memory");
      } else {
        asm volatile("s_waitcnt vmcnt(0)" ::: "memory");
      }

      // ---- K fragments from LDS (swizzled): 8 x ds_read_b128, reused qp=0,1
      bf16x8 kfr[2][4];
      const char* kx = (const char*)lX[w][half] + c16 * 128;
#pragma unroll
      for (int kc = 0; kc < 2; kc++)
#pragma unroll
        for (int mt = 0; mt < 4; mt++)
          kfr[kc][mt] = *(const bf16x8*)(kx + mt * 2048 + (((kc * 4 + quad) ^ c7) << 4));

      // ---- QK^T + fixed-M softmax (S^T layout), both 32-q substrips;
      //      P overwrites the K region of lX[w][half] (K already in kfr).
#pragma unroll
      for (int qp = 0; qp < 2; qp++) {
        f32x4 st[4][2];
#pragma unroll
        for (int mt = 0; mt < 4; mt++) {
          st[mt][0] = f32x4{0.f, 0.f, 0.f, 0.f};
          st[mt][1] = f32x4{0.f, 0.f, 0.f, 0.f};
        }
        __builtin_amdgcn_s_setprio(1);
#pragma unroll
        for (int kc = 0; kc < 2; kc++)
#pragma unroll
          for (int mt = 0; mt < 4; mt++) {
            st[mt][0] = mfma16(kfr[kc][mt], qf[qp * 2 + 0][kc], st[mt][0]);
            st[mt][1] = mfma16(kfr[kc][mt], qf[qp * 2 + 1][kc], st[mt][1]);
          }
        __builtin_amdgcn_s_setprio(0);

        // causal mask on the diagonal tile (uniform branch)
        if (j == jmax) {
#pragma unroll
          for (int nt = 0; nt < 2; nt++) {
            const int qg = q0w + qp * 32 + nt * 16 + c16;
#pragma unroll
            for (int mt = 0; mt < 4; mt++)
#pragma unroll
              for (int rr = 0; rr < 4; rr++) {
                const int key = j * 128 + half * 64 + mt * 16 + quad * 4 + rr;
                if (key > qg) st[mt][nt][rr] = -1.0e9f;
              }
          }
        }

        // P = exp2(s); l += sum(P); pack P -> lX[w][half] rows [q][64 keys].
#pragma unroll
        for (int nt = 0; nt < 2; nt++) {
          float sum0 = 0.f, sum1 = 0.f;
          const int prow = qp * 32 + nt * 16 + c16;
          const size_t pbase = (size_t)prow * 128;
#pragma unroll
          for (int mt = 0; mt < 4; mt++) {
            float p0 = __builtin_amdgcn_exp2f(st[mt][nt][0]);
            float p1 = __builtin_amdgcn_exp2f(st[mt][nt][1]);
            float p2 = __builtin_amdgcn_exp2f(st[mt][nt][2]);
            float p3 = __builtin_amdgcn_exp2f(st[mt][nt][3]);
            sum0 += p0 + p1;
            sum1 += p2 + p3;
            const unsigned int lo = pack_hi(p0, p1);
            const unsigned int hi = pack_hi(p2, p3);
            const int chunk = mt * 2 + (quad >> 1);  // 8 x 16B chunks per row
            uint2* dst = (uint2*)((char*)lX[w][half] + pbase +
                                  ((chunk ^ (prow & 7)) << 4) + (quad & 1) * 8);
            *dst = make_uint2(lo, hi);
          }
          float sum = sum0 + sum1;
          sum += __shfl_xor(sum, 16);
          sum += __shfl_xor(sum, 32);
          ls[qp * 2 + nt] += sum;
        }
      }
      // lX[w][half] now holds P; same-wave write->read (in order): no barrier.

      // ---- O^T += Vt(half) . P(half)^T : vf transient (16 regs, r14-style)
#pragma unroll
      for (int kc2 = 0; kc2 < 2; kc2++) {
        int4 vf[4];
#pragma unroll
        for (int mt = 0; mt < 4; mt++)
          vf[mt] = *(const int4*)(vbase + ((mt * 16 + c16) << 7) +
                                  (half * 8 + kc2 * 4 + quad) * 8);
        bf16x8 pb[4];
#pragma unroll
        for (int ntq = 0; ntq < 4; ntq++) {
          const int prow = ntq * 16 + c16;
          pb[ntq] = *(const bf16x8*)((const char*)lX[w][half] + (size_t)prow * 128 +
                                     (((kc2 * 4 + quad) ^ (prow & 7)) << 4));
        }
        __builtin_amdgcn_s_setprio(1);
#pragma unroll
        for (int mt = 0; mt < 4; mt++) {
          bf16x8 a = __builtin_bit_cast(bf16x8, vf[mt]);
#pragma unroll
          for (int ntq = 0; ntq < 4; ntq++)
            o[mt][ntq] = mfma16(a, pb[ntq], o[mt][ntq]);
        }
        __builtin_amdgcn_s_setprio(0);
      }
    }
  }

  // drain any in-flight (dead) staging before lX is reused as merge buffer
  asm volatile("s_waitcnt vmcnt(0)" ::: "memory");

  // ---- spill this wave's O^T (fp32, d-major [d][q]) into its own lX region.
  float* oL = (float*)lX[w];
#pragma unroll
  for (int mt = 0; mt < 4; mt++)
#pragma unroll
    for (int ntq = 0; ntq < 4; ntq++)
#pragma unroll
      for (int rr = 0; rr < 4; rr++)
        oL[(mt * 16 + quad * 4 + rr) * 64 + ntq * 16 + c16] = o[mt][ntq][rr];
  if (quad == 0) {
#pragma unroll
    for (int ntq = 0; ntq < 4; ntq++) lL[w][ntq * 16 + c16] = ls[ntq];
  }
  __syncthreads();

  // ---- block reduce over the 4 split-K partials; write bf16 Ob directly.
  const int q = tid & 63, dq = tid >> 6;
  const float lsum = lL[0][q] + lL[1][q] + lL[2][q] + lL[3][q];
  const float inv = 1.f / lsum;
  uint16_t t[16] __attribute__((aligned(16)));
#pragma unroll
  for (int i = 0; i < 16; i++) {
    const int d = dq * 16 + i;
    const int off = d * 64 + q;
    float s = ((const float*)lX[0])[off] + ((const float*)lX[1])[off] +
              ((const float*)lX[2])[off] + ((const float*)lX[3])[off];
    t[i] = f2bf(s * inv);
  }
  uint16_t* dst = Ob + (size_t)(q0w + q) * 1024 + h * 64 + dq * 16;
  *(int4*)dst = *(const int4*)t;
  *(int4*)(dst + 8) = *(const int4*)(t + 8);
#undef STAGE_K
}

// ---------------------------------------------------------------------------
extern "C" void kernel_launch(void* const* d_in, const int* in_sizes, int n_in,
                              void* d_out, int out_size, void* d_ws, size_t ws_size,
                              hipStream_t stream) {
  const float* x      = (const float*)d_in[0];   // fp32 [1][4096][1024]
  // d_in[1] = attention_mask (fp32): analytically causal, never read
  const float* W_attn = (const float*)d_in[2];   // fp32 [1024][3072]
  const float* b_attn = (const float*)d_in[3];   // fp32 [3072]
  const float* W_proj = (const float*)d_in[4];   // fp32 [1024][1024]
  const float* b_proj = (const float*)d_in[5];   // fp32 [1024]
  float* out = (float*)d_out;                    // fp32 [4096][1024]

  // Workspace (48 MB).
  char* ws = (char*)d_ws;
  uint16_t* Ob  = (uint16_t*)(ws);                    // [0,8MB): attn out bf16 [4096][1024]
  uint16_t* wtA = (uint16_t*)(ws + 8388608);          // [8,14MB): W_attn^T bf16
  uint16_t* wtP = (uint16_t*)(ws + 14680064);         // [14,16MB): W_proj^T bf16
  uint16_t* Qb  = (uint16_t*)(ws + 16777216);         // [16,24MB): Q bf16 (prescaled QSCALE)
  uint16_t* Kb  = (uint16_t*)(ws + 25165824);         // [24,32MB): K bf16
  uint16_t* Vtb = (uint16_t*)(ws + 33554432);         // [32,40MB): V^T tile-blocked bf16
  uint16_t* xb  = (uint16_t*)(ws + 41943040);         // [40,48MB): x bf16

  f2b_k<<<2048, 256, 0, stream>>>(x, xb, 4096 * 1024);
  transpose2_f2b<<<dim3(64, 16), 256, 0, stream>>>(W_attn, wtA, W_proj, wtP);
  gemm_bt<0><<<dim3(24, 32), 256, 0, stream>>>(xb, wtA, b_attn, Qb, Kb, Vtb, nullptr);
  attn_kernel<<<dim3(1024), 256, 0, stream>>>(Qb, Kb, Vtb, Ob);
  gemm_bt<1><<<dim3(8, 32), 256, 0, stream>>>(Ob, wtP, b_proj, nullptr, nullptr, nullptr, out);
}